// Round 6
// baseline (101.891 us; speedup 1.0000x reference)
//
#include <hip/hip_runtime.h>
#include <hip/hip_bf16.h>
#include <stdint.h>

typedef __attribute__((ext_vector_type(4)))  int   i32x4;
typedef __attribute__((ext_vector_type(8)))  int   i32x8;
typedef __attribute__((ext_vector_type(16))) float f32x16;

#define MDIM   4096
#define NDIM   4096
#define KBYTES 2048   // K=4096 fp4 elems -> 2048 packed bytes per row
#define NKBLK  128    // K/32 scale blocks per row

#define BM   256
#define BN   256
#define BKB  128                 // K-bytes per tile (= 256 fp4 elems = 8 scale blocks)
#define KT   (KBYTES / BKB)      // 16 K-tiles

#define BARF()  asm volatile("s_barrier" ::: "memory")
#define LGKM0() asm volatile("s_waitcnt lgkmcnt(0)" ::: "memory")
// Counted drain (T4): each issue group = 4 global_load_lds + 4 scale loads = 8.
// At tile end: outstanding = [kt+1.kw1 grp(8)][kt+2.kw0 grp(8)]; vmcnt(8)
// drains kt+1 fully, leaves kt+2.kw0 in flight.
#define VMC8()  asm volatile("s_waitcnt vmcnt(8)" ::: "memory")

// ---------------- repack: int32-per-byte -> packed bytes ----------------
__global__ void repack_bytes(const int* __restrict__ a, const int* __restrict__ b,
                             uint32_t* __restrict__ ap, uint32_t* __restrict__ bp) {
  const size_t n4 = (size_t)MDIM * KBYTES / 4;
  for (size_t i = (size_t)blockIdx.x * blockDim.x + threadIdx.x; i < n4;
       i += (size_t)gridDim.x * blockDim.x) {
    i32x4 va = *(const i32x4*)(a + i * 4);
    ap[i] = (uint32_t)(va.x & 255) | ((uint32_t)(va.y & 255) << 8) |
            ((uint32_t)(va.z & 255) << 16) | ((uint32_t)(va.w & 255) << 24);
    i32x4 vb = *(const i32x4*)(b + i * 4);
    bp[i] = (uint32_t)(vb.x & 255) | ((uint32_t)(vb.y & 255) << 8) |
            ((uint32_t)(vb.z & 255) << 16) | ((uint32_t)(vb.w & 255) << 24);
  }
}

// ---- scales: float biased-exp -> uint8 E8M0, layout [kb][m&31][m>>5] ----------
// 32x32 fragment: lane needs rows {ms*32 + (l&31) : ms=0..3} at fixed kb ->
// one dword at sat[kb*4096 + (l&31)*128 + (rowbase>>5)].
__global__ void repack_scales(const float* __restrict__ sa, const float* __restrict__ sb,
                              uint8_t* __restrict__ sat, uint8_t* __restrict__ sbt) {
  int t = blockIdx.x * blockDim.x + threadIdx.x;
  if (t >= MDIM * NKBLK) return;
  int m  = t >> 7;     // row
  int kb = t & 127;    // k-block
  int o  = kb * 4096 + (m & 31) * 128 + (m >> 5);
  sat[o] = (uint8_t)(int)sa[t];
  sbt[o] = (uint8_t)(int)sb[t];
}

__device__ __forceinline__ i32x8 frag8(i32x4 v) {
  i32x8 r = {v.x, v.y, v.z, v.w, 0, 0, 0, 0};
  return r;
}

__device__ __forceinline__ int sbyteu(uint32_t v, int i) {
  return (int)((v >> (i * 8)) & 0xffu);
}

// ---- MXFP4 GEMM, 256x256 tile, 8 waves, 32x32x64 MFMA, counted-vmcnt pipeline --
// LDS: [buf(2)][mat(2)][kw(2)][row(256)][64B] = 128 KB (same planes as R5).
// Tile = 4 MFMA k-steps of 64 elems; kw-half = 2 k-steps. 4 phases/tile.
__global__ __launch_bounds__(512, 2) void mxfp4_gemm(
    const uint8_t* __restrict__ ap, const uint8_t* __restrict__ bp,
    const uint8_t* __restrict__ sat, const uint8_t* __restrict__ sbt,
    float* __restrict__ out) {
  extern __shared__ uint8_t lds[];

  const int tid  = threadIdx.x;
  const int lane = tid & 63;
  const int w    = tid >> 6;        // wave 0..7
  const int wrow = w >> 2;          // 2 M-waves: rows wrow*128..+127
  const int wcol = w & 3;           // 4 N-waves: cols wcol*64..+63
  const int h    = lane >> 5;       // k-half within the 64-elem MFMA K
  const int r31  = lane & 31;       // fragment row/col
  const int rswz = (r31 >> 1) & 3;  // read-side xor: storage slot d holds global d^((row>>1)&3)

  const int bx = blockIdx.x;
  const int by = blockIdx.y;

  const uint8_t* aBase = ap + (size_t)(by * BM) * KBYTES;
  const uint8_t* bBase = bp + (size_t)(bx * BN) * KBYTES;

  // staging (unchanged from R5): lane -> row (lane>>2), dest slot (lane&3);
  // source slot pre-swizzled with the same involution ((row>>1)&3).
  const int soff4 = (lane >> 2) * KBYTES + (((lane & 3) ^ ((lane >> 3) & 3)) * 16);
  const int arow0 = w * 32;         // each wave stages 32 A-rows + 32 B-rows

#define PLANE(bufi, mat, kwX) (lds + (bufi) * 65536 + (mat) * 32768 + (kwX) * 16384)

#define STAGE_HALF(bufi, ktX, kwX)                                                        \
  do {                                                                                    \
    const uint8_t* _sa = aBase + (size_t)arow0 * KBYTES + (ktX) * BKB + (kwX) * 64 + soff4; \
    const uint8_t* _sb = bBase + (size_t)arow0 * KBYTES + (ktX) * BKB + (kwX) * 64 + soff4; \
    uint8_t* _da = PLANE(bufi, 0, kwX) + arow0 * 64;                                      \
    uint8_t* _db = PLANE(bufi, 1, kwX) + arow0 * 64;                                      \
    __builtin_amdgcn_global_load_lds((__attribute__((address_space(1))) void*)_sa,        \
        (__attribute__((address_space(3))) void*)_da, 16, 0, 0);                          \
    __builtin_amdgcn_global_load_lds((__attribute__((address_space(1))) void*)(_sa + 16 * KBYTES), \
        (__attribute__((address_space(3))) void*)(_da + 1024), 16, 0, 0);                 \
    __builtin_amdgcn_global_load_lds((__attribute__((address_space(1))) void*)_sb,        \
        (__attribute__((address_space(3))) void*)(_db), 16, 0, 0);                        \
    __builtin_amdgcn_global_load_lds((__attribute__((address_space(1))) void*)(_sb + 16 * KBYTES), \
        (__attribute__((address_space(3))) void*)(_db + 1024), 16, 0, 0);                 \
  } while (0)

  // scale pointers: byte for (row m, block kb) at sat[kb*4096 + (m&31)*128 + m>>5].
  // This lane's A rows: wrow*128 + ms*32 + r31 -> bytes ms=0..3 of one dword.
  // This lane's B rows: wcol*64 + ns*32 + r31 -> bytes ns=0..1 of one ushort.
  // kb = kt*8 + ks*2 + h.
  const uint8_t* sApH = sat + (size_t)r31 * 128 + by * 8 + wrow * 4 + (size_t)h * 4096;
  const uint8_t* sBpH = sbt + (size_t)r31 * 128 + bx * 8 + wcol * 2 + (size_t)h * 4096;
#define LDSA(ktX, ks2X) (*(const uint32_t*)(sApH + (size_t)((ktX) * 8 + (ks2X) * 2) * 4096))
#define LDSB(ktX, ks2X) ((uint32_t)*(const uint16_t*)(sBpH + (size_t)((ktX) * 8 + (ks2X) * 2) * 4096))

  f32x16 acc[4][2] = {};
  i32x4 af[4], bf[2];
  // scale generations: kw0 (staged 2 tiles ahead): c/m/n; kw1 (1 ahead): c/n.
  uint32_t sA0c0, sA0c1, sA0m0, sA0m1, sA0n0, sA0n1;
  uint32_t sA1c0, sA1c1, sA1n0, sA1n1;
  uint32_t sB0c0, sB0c1, sB0m0, sB0m1, sB0n0, sB0n1;
  uint32_t sB1c0, sB1c1, sB1n0, sB1n1;

  // ------- prologue: stage kt0.kw0 | kt0.kw1 | kt1.kw0 (+scales), vmcnt(8) -------
  STAGE_HALF(0, 0, 0);
  sA0c0 = LDSA(0, 0); sA0c1 = LDSA(0, 1); sB0c0 = LDSB(0, 0); sB0c1 = LDSB(0, 1);
  STAGE_HALF(0, 0, 1);
  sA1c0 = LDSA(0, 2); sA1c1 = LDSA(0, 3); sB1c0 = LDSB(0, 2); sB1c1 = LDSB(0, 3);
  STAGE_HALF(1, 1, 0);
  sA0m0 = LDSA(1, 0); sA0m1 = LDSA(1, 1); sB0m0 = LDSB(1, 0); sB0m1 = LDSB(1, 1);
  VMC8();          // kt0 fully landed; kt1.kw0 group still in flight
  BARF();

#define READ_FRAGS(kwX, slotbase)                                                         \
  do {                                                                                    \
    const int _sl = (((slotbase) + h) ^ rswz) * 16;                                       \
    const uint8_t* _A = PLANE(cur, 0, kwX);                                               \
    const uint8_t* _B = PLANE(cur, 1, kwX);                                               \
    bf[0] = *(const i32x4*)(_B + (wcol * 64 + 0 * 32 + r31) * 64 + _sl);                  \
    bf[1] = *(const i32x4*)(_B + (wcol * 64 + 1 * 32 + r31) * 64 + _sl);                  \
    af[0] = *(const i32x4*)(_A + (wrow * 128 + 0 * 32 + r31) * 64 + _sl);                 \
    af[1] = *(const i32x4*)(_A + (wrow * 128 + 1 * 32 + r31) * 64 + _sl);                 \
    af[2] = *(const i32x4*)(_A + (wrow * 128 + 2 * 32 + r31) * 64 + _sl);                 \
    af[3] = *(const i32x4*)(_A + (wrow * 128 + 3 * 32 + r31) * 64 + _sl);                 \
  } while (0)

#define MFMA8(sAv, sBv)                                                                   \
  do {                                                                                    \
    _Pragma("unroll")                                                                     \
    for (int ms = 0; ms < 4; ++ms) {                                                      \
      const int _sa = sbyteu((sAv), ms);                                                  \
      _Pragma("unroll")                                                                   \
      for (int ns = 0; ns < 2; ++ns)                                                      \
        acc[ms][ns] = __builtin_amdgcn_mfma_scale_f32_32x32x64_f8f6f4(                    \
            frag8(af[ms]), frag8(bf[ns]), acc[ms][ns], 4, 4,                              \
            0, _sa, 0, sbyteu((sBv), ns));                                                \
    }                                                                                     \
  } while (0)

  for (int kt = 0; kt < KT; ++kt) {
    const int cur = kt & 1;
    const int nxt = cur ^ 1;
    const int kt1 = (kt + 1) & (KT - 1);   // modulo: tail stages junk into dead planes
    const int kt2 = (kt + 2) & (KT - 1);

    // ===== P0: k-step 0 (kw0, slot h); issue {kt+1.kw1 stage + its scales} =======
    READ_FRAGS(0, 0);
    STAGE_HALF(nxt, kt1, 1);
    sA1n0 = LDSA(kt1, 2); sA1n1 = LDSA(kt1, 3);
    sB1n0 = LDSB(kt1, 2); sB1n1 = LDSB(kt1, 3);
    BARF(); LGKM0();
    __builtin_amdgcn_s_setprio(1);
    MFMA8(sA0c0, sB0c0);
    __builtin_amdgcn_s_setprio(0);
    BARF();

    // ===== P1: k-step 1 (kw0, slot 2+h) ==========================================
    READ_FRAGS(0, 2);
    BARF(); LGKM0();
    __builtin_amdgcn_s_setprio(1);
    MFMA8(sA0c1, sB0c1);
    __builtin_amdgcn_s_setprio(0);
    BARF();

    // ===== P2: k-step 2 (kw1, slot h); issue {kt+2.kw0 stage + its scales} =======
    // cur.kw0 reads all drained by P1's LGKM0+barrier -> safe to overwrite.
    READ_FRAGS(1, 0);
    STAGE_HALF(cur, kt2, 0);
    sA0n0 = LDSA(kt2, 0); sA0n1 = LDSA(kt2, 1);
    sB0n0 = LDSB(kt2, 0); sB0n1 = LDSB(kt2, 1);
    BARF(); LGKM0();
    __builtin_amdgcn_s_setprio(1);
    MFMA8(sA1c0, sB1c0);
    __builtin_amdgcn_s_setprio(0);
    BARF();

    // ===== P3: k-step 3 (kw1, slot 2+h); rotate scales; counted drain ============
    READ_FRAGS(1, 2);
    BARF(); LGKM0();
    __builtin_amdgcn_s_setprio(1);
    MFMA8(sA1c1, sB1c1);
    __builtin_amdgcn_s_setprio(0);
    sA0c0 = sA0m0; sA0c1 = sA0m1; sA0m0 = sA0n0; sA0m1 = sA0n1;
    sB0c0 = sB0m0; sB0c1 = sB0m1; sB0m0 = sB0n0; sB0m1 = sB0n1;
    sA1c0 = sA1n0; sA1c1 = sA1n1; sB1c0 = sB1n0; sB1c1 = sB1n1;
    VMC8();
    BARF();
  }

  // epilogue: 32x32 D mapping: row=(reg&3)+8*(reg>>2)+4*h, col=r31
  float* ob = out + (size_t)(by * BM + wrow * 128) * NDIM + bx * BN + wcol * 64;
#pragma unroll
  for (int ms = 0; ms < 4; ++ms)
#pragma unroll
    for (int ns = 0; ns < 2; ++ns) {
#pragma unroll
      for (int r = 0; r < 16; ++r) {
        const int row = ms * 32 + (r & 3) + 8 * (r >> 2) + 4 * h;
        ob[(size_t)row * NDIM + ns * 32 + r31] = acc[ms][ns][r];
      }
    }
#undef STAGE_HALF
#undef PLANE
#undef READ_FRAGS
#undef MFMA8
#undef LDSA
#undef LDSB
}

extern "C" void kernel_launch(void* const* d_in, const int* in_sizes, int n_in,
                              void* d_out, int out_size, void* d_ws, size_t ws_size,
                              hipStream_t stream) {
  (void)in_sizes; (void)n_in; (void)out_size; (void)ws_size;
  const int*   a  = (const int*)d_in[0];
  const int*   b  = (const int*)d_in[1];
  const float* sa = (const float*)d_in[2];
  const float* sb = (const float*)d_in[3];
  float* out = (float*)d_out;

  uint8_t* ws = (uint8_t*)d_ws;
  uint32_t* ap = (uint32_t*)ws;                          // 8 MB packed A
  uint32_t* bp = (uint32_t*)(ws + (8u << 20));           // 8 MB packed B
  uint8_t*  sat = ws + (16u << 20);                      // 512 KB scales A
  uint8_t*  sbt = ws + (16u << 20) + (512u << 10);       // 512 KB scales B

  repack_bytes<<<2048, 256, 0, stream>>>(a, b, ap, bp);
  repack_scales<<<(MDIM * NKBLK + 255) / 256, 256, 0, stream>>>(sa, sb, sat, sbt);

  hipFuncSetAttribute((const void*)mxfp4_gemm,
                      hipFuncAttributeMaxDynamicSharedMemorySize, 131072);

  dim3 grid(NDIM / BN, MDIM / BM);   // 16 x 16 = 256 blocks = 1/CU
  mxfp4_gemm<<<grid, 512, 131072, stream>>>((const uint8_t*)ap, (const uint8_t*)bp,
                                            sat, sbt, out);
}

// Round 7
// 71.330 us; speedup vs baseline: 1.4285x; 1.4285x over previous
//
#include <hip/hip_runtime.h>
#include <hip/hip_bf16.h>
#include <stdint.h>

typedef __attribute__((ext_vector_type(4))) int   i32x4;
typedef __attribute__((ext_vector_type(8))) int   i32x8;
typedef __attribute__((ext_vector_type(4))) float f32x4;
typedef __attribute__((ext_vector_type(2))) unsigned int u32x2;

#define MDIM   4096
#define NDIM   4096
#define KBYTES 2048   // K=4096 fp4 elems -> 2048 packed bytes per row
#define NKBLK  128    // K/32 scale blocks per row

#define BM   256
#define BN   256
#define BKB  128                 // K-bytes per tile (= 256 fp4 elems = 8 scale blocks)
#define KT   (KBYTES / BKB)      // 16 K-tiles

#define BARF()  asm volatile("s_barrier" ::: "memory")
#define LGKM0() asm volatile("s_waitcnt lgkmcnt(0)" ::: "memory")
// Counted drain (T4). Per-tile vmem issue: P0 group = 4 data + 4 scale ops (8),
// P2 group = 4 data ops. Tile-end outstanding = [prev-leftover kw0 (4)]
// [P0 grp (8)][P2 grp (4)] = 16; vmcnt(4) drains all of tile kt+1 (data+scales),
// leaves kt+2.kw0 in flight.
#define VMC4()  asm volatile("s_waitcnt vmcnt(4)" ::: "memory")

// ---------------- repack: int32-per-byte -> packed bytes ----------------
__global__ void repack_bytes(const int* __restrict__ a, const int* __restrict__ b,
                             uint32_t* __restrict__ ap, uint32_t* __restrict__ bp) {
  const size_t n4 = (size_t)MDIM * KBYTES / 4;
  for (size_t i = (size_t)blockIdx.x * blockDim.x + threadIdx.x; i < n4;
       i += (size_t)gridDim.x * blockDim.x) {
    i32x4 va = *(const i32x4*)(a + i * 4);
    ap[i] = (uint32_t)(va.x & 255) | ((uint32_t)(va.y & 255) << 8) |
            ((uint32_t)(va.z & 255) << 16) | ((uint32_t)(va.w & 255) << 24);
    i32x4 vb = *(const i32x4*)(b + i * 4);
    bp[i] = (uint32_t)(vb.x & 255) | ((uint32_t)(vb.y & 255) << 8) |
            ((uint32_t)(vb.z & 255) << 16) | ((uint32_t)(vb.w & 255) << 24);
  }
}

// ---- scales: float -> uint8 E8M0, per-(K-tile, 256-row-block) contiguous 2KB ----
// Layout: [kt(16)][rowblk(16)][kbit(8)][m&15 (16)][ (m>>4)&15 (16) ]  (512 KB).
// Within one (kt,rowblk) 2KB block, a lane reads its 8 A-bytes (ms=0..7) as one
// b64 at kbit*256 + l15*16 + wrow*8, or its 4 B-bytes (ns=0..3) as one b32.
__global__ void repack_scales(const float* __restrict__ sa, const float* __restrict__ sb,
                              uint8_t* __restrict__ satT, uint8_t* __restrict__ sbtT) {
  int t = blockIdx.x * blockDim.x + threadIdx.x;
  if (t >= MDIM * NKBLK) return;
  int m  = t >> 7;     // row
  int kb = t & 127;    // k-block
  int o  = ((((kb >> 3) * 16 + (m >> 8)) * 8 + (kb & 7)) * 16 + (m & 15)) * 16
           + ((m >> 4) & 15);
  satT[o] = (uint8_t)(int)sa[t];
  sbtT[o] = (uint8_t)(int)sb[t];
}

__device__ __forceinline__ i32x8 frag8(i32x4 v) {
  i32x8 r = {v.x, v.y, v.z, v.w, 0, 0, 0, 0};
  return r;
}

__device__ __forceinline__ int sbyte2(u32x2 p, int i) {
  return (int)((i < 4 ? (p.x >> (i * 8)) : (p.y >> ((i - 4) * 8))) & 0xffu);
}

// ---- MXFP4 GEMM: R5 structure (16x16x128, kw-half dbuf, counted vmcnt) with ----
// ---- ALL scales staged via global_load_lds -> no vmem-dependent VGPRs in loop --
// LDS: data [buf(2)][mat(2)][kw(2)][row(256)][64B] = 128 KB; scales at +128K:
//      [buf(2)][A 2KB | B 2KB] = 8 KB. Total 136 KB.
__global__ __launch_bounds__(512, 2) void mxfp4_gemm(
    const uint8_t* __restrict__ ap, const uint8_t* __restrict__ bp,
    const uint8_t* __restrict__ satT, const uint8_t* __restrict__ sbtT,
    float* __restrict__ out) {
  extern __shared__ uint8_t lds[];

  const int tid  = threadIdx.x;
  const int lane = tid & 63;
  const int w    = tid >> 6;        // wave 0..7
  const int wrow = w >> 2;          // 2 M-waves
  const int wcol = w & 3;           // 4 N-waves
  const int g    = lane >> 4;       // k-group 0..3 (32 fp4 elems each)
  const int l15  = lane & 15;

  const int bx = blockIdx.x;
  const int by = blockIdx.y;

  const uint8_t* aBase = ap + (size_t)(by * BM) * KBYTES;
  const uint8_t* bBase = bp + (size_t)(bx * BN) * KBYTES;

  // read-side swizzle (R5, HW-verified conflict-free): LDS[row][d] holds
  // global slot d ^ ((row>>1)&3); fragment rows have (row>>1)&3 == (l15>>1)&3.
  const int rdslot = (g ^ ((l15 >> 1) & 3)) * 16;
  // stage side: lane -> row (lane>>2), dest slot lane&3 (linear), source slot
  // pre-swizzled with the same involution.
  const int soff4 = (lane >> 2) * KBYTES + (((lane & 3) ^ ((lane >> 3) & 3)) * 16);
  const int arow0 = w * 32;         // each wave stages 32 A-rows + 32 B-rows

#define PLANE(bufi, mat, kwX) (lds + (bufi) * 65536 + (mat) * 32768 + (kwX) * 16384)
#define SCB(bufi)             (lds + 131072 + (bufi) * 4096)

#define STAGE_HALF(bufi, ktX, kwX)                                                        \
  do {                                                                                    \
    const uint8_t* _sa = aBase + (size_t)arow0 * KBYTES + (ktX) * BKB + (kwX) * 64 + soff4; \
    const uint8_t* _sb = bBase + (size_t)arow0 * KBYTES + (ktX) * BKB + (kwX) * 64 + soff4; \
    uint8_t* _da = PLANE(bufi, 0, kwX) + arow0 * 64;                                      \
    uint8_t* _db = PLANE(bufi, 1, kwX) + arow0 * 64;                                      \
    __builtin_amdgcn_global_load_lds((__attribute__((address_space(1))) void*)_sa,        \
        (__attribute__((address_space(3))) void*)_da, 16, 0, 0);                          \
    __builtin_amdgcn_global_load_lds((__attribute__((address_space(1))) void*)(_sa + 16 * KBYTES), \
        (__attribute__((address_space(3))) void*)(_da + 1024), 16, 0, 0);                 \
    __builtin_amdgcn_global_load_lds((__attribute__((address_space(1))) void*)_sb,        \
        (__attribute__((address_space(3))) void*)(_db), 16, 0, 0);                        \
    __builtin_amdgcn_global_load_lds((__attribute__((address_space(1))) void*)(_sb + 16 * KBYTES), \
        (__attribute__((address_space(3))) void*)(_db + 1024), 16, 0, 0);                 \
  } while (0)

// All 8 waves stage the tile's 4 KB of scales redundantly (same src, same dest,
// identical values -> benign; keeps per-wave vmcnt accounting uniform).
#define STAGE_SCALES(bufi, ktX)                                                           \
  do {                                                                                    \
    const uint8_t* _ssa = satT + ((size_t)(ktX) * 16 + by) * 2048 + lane * 16;            \
    const uint8_t* _ssb = sbtT + ((size_t)(ktX) * 16 + bx) * 2048 + lane * 16;            \
    uint8_t* _dsc = SCB(bufi);                                                            \
    __builtin_amdgcn_global_load_lds((__attribute__((address_space(1))) void*)_ssa,       \
        (__attribute__((address_space(3))) void*)_dsc, 16, 0, 0);                         \
    __builtin_amdgcn_global_load_lds((__attribute__((address_space(1))) void*)(_ssa + 1024), \
        (__attribute__((address_space(3))) void*)(_dsc + 1024), 16, 0, 0);                \
    __builtin_amdgcn_global_load_lds((__attribute__((address_space(1))) void*)_ssb,       \
        (__attribute__((address_space(3))) void*)(_dsc + 2048), 16, 0, 0);                \
    __builtin_amdgcn_global_load_lds((__attribute__((address_space(1))) void*)(_ssb + 1024), \
        (__attribute__((address_space(3))) void*)(_dsc + 3072), 16, 0, 0);                \
  } while (0)

  f32x4 acc[8][4] = {};
  i32x4 a0[4], a1[4], bf[4];

  // ---------------- prologue ----------------
  STAGE_HALF(0, 0, 0);
  STAGE_SCALES(0, 0);            // G1 = 8 ops
  STAGE_HALF(0, 0, 1);           // G2 = 4 ops
  STAGE_HALF(1, 1, 0);           // G3 = 4 ops
  VMC4();                        // drain G1+G2 (tile 0 complete); G3 in flight
  BARF();

  for (int kt = 0; kt < KT; ++kt) {
    const int cur = kt & 1;
    const int nxt = cur ^ 1;
    const uint8_t* A0  = PLANE(cur, 0, 0);
    const uint8_t* B0  = PLANE(cur, 1, 0);
    const uint8_t* A1p = PLANE(cur, 0, 1);
    const uint8_t* B1p = PLANE(cur, 1, 1);
    const int kt1 = (kt + 1) & (KT - 1);   // tail wraps stage junk into dead slots
    const int kt2 = (kt + 2) & (KT - 1);

    // ===== P0: frags kw0 (bf + a0..3) + ALL tile scales from LDS; issue
    //           {kt+1.kw1 data + kt+1 scales} ====================================
#pragma unroll
    for (int ns = 0; ns < 4; ++ns)
      bf[ns] = *(const i32x4*)(B0 + (wcol * 64 + ns * 16 + l15) * 64 + rdslot);
#pragma unroll
    for (int ms = 0; ms < 4; ++ms)
      a0[ms] = *(const i32x4*)(A0 + (wrow * 128 + ms * 16 + l15) * 64 + rdslot);
    const uint8_t* scb = SCB(cur);
    const u32x2   sAk0 = *(const u32x2*)(scb + (0 + g) * 256 + l15 * 16 + wrow * 8);
    const u32x2   sAk1 = *(const u32x2*)(scb + (4 + g) * 256 + l15 * 16 + wrow * 8);
    const uint32_t sBk0 = *(const uint32_t*)(scb + 2048 + (0 + g) * 256 + l15 * 16 + wcol * 4);
    const uint32_t sBk1 = *(const uint32_t*)(scb + 2048 + (4 + g) * 256 + l15 * 16 + wcol * 4);
    STAGE_HALF(nxt, kt1, 1);
    STAGE_SCALES(nxt, kt1);
    BARF(); LGKM0();
    __builtin_amdgcn_s_setprio(1);
#pragma unroll
    for (int ms = 0; ms < 4; ++ms) {
      const int sa = sbyte2(sAk0, ms);
#pragma unroll
      for (int ns = 0; ns < 4; ++ns)
        acc[ms][ns] = __builtin_amdgcn_mfma_scale_f32_16x16x128_f8f6f4(
            frag8(a0[ms]), frag8(bf[ns]), acc[ms][ns], 4, 4,
            0, sa, 0, (int)((sBk0 >> (ns * 8)) & 0xffu));
    }
    __builtin_amdgcn_s_setprio(0);
    BARF();

    // ===== P1: frags kw0 (a4..7) =================================================
#pragma unroll
    for (int ms = 0; ms < 4; ++ms)
      a1[ms] = *(const i32x4*)(A0 + (wrow * 128 + (ms + 4) * 16 + l15) * 64 + rdslot);
    BARF(); LGKM0();
    __builtin_amdgcn_s_setprio(1);
#pragma unroll
    for (int ms = 0; ms < 4; ++ms) {
      const int sa = sbyte2(sAk0, ms + 4);
#pragma unroll
      for (int ns = 0; ns < 4; ++ns)
        acc[ms + 4][ns] = __builtin_amdgcn_mfma_scale_f32_16x16x128_f8f6f4(
            frag8(a1[ms]), frag8(bf[ns]), acc[ms + 4][ns], 4, 4,
            0, sa, 0, (int)((sBk0 >> (ns * 8)) & 0xffu));
    }
    __builtin_amdgcn_s_setprio(0);
    BARF();

    // ===== P2: frags kw1 (bf + a0..3); issue {kt+2.kw0 data} =====================
#pragma unroll
    for (int ns = 0; ns < 4; ++ns)
      bf[ns] = *(const i32x4*)(B1p + (wcol * 64 + ns * 16 + l15) * 64 + rdslot);
#pragma unroll
    for (int ms = 0; ms < 4; ++ms)
      a0[ms] = *(const i32x4*)(A1p + (wrow * 128 + ms * 16 + l15) * 64 + rdslot);
    STAGE_HALF(cur, kt2, 0);
    BARF(); LGKM0();
    __builtin_amdgcn_s_setprio(1);
#pragma unroll
    for (int ms = 0; ms < 4; ++ms) {
      const int sa = sbyte2(sAk1, ms);
#pragma unroll
      for (int ns = 0; ns < 4; ++ns)
        acc[ms][ns] = __builtin_amdgcn_mfma_scale_f32_16x16x128_f8f6f4(
            frag8(a0[ms]), frag8(bf[ns]), acc[ms][ns], 4, 4,
            0, sa, 0, (int)((sBk1 >> (ns * 8)) & 0xffu));
    }
    __builtin_amdgcn_s_setprio(0);
    BARF();

    // ===== P3: frags kw1 (a4..7); counted drain ==================================
#pragma unroll
    for (int ms = 0; ms < 4; ++ms)
      a1[ms] = *(const i32x4*)(A1p + (wrow * 128 + (ms + 4) * 16 + l15) * 64 + rdslot);
    BARF(); LGKM0();
    __builtin_amdgcn_s_setprio(1);
#pragma unroll
    for (int ms = 0; ms < 4; ++ms) {
      const int sa = sbyte2(sAk1, ms + 4);
#pragma unroll
      for (int ns = 0; ns < 4; ++ns)
        acc[ms + 4][ns] = __builtin_amdgcn_mfma_scale_f32_16x16x128_f8f6f4(
            frag8(a1[ms]), frag8(bf[ns]), acc[ms + 4][ns], 4, 4,
            0, sa, 0, (int)((sBk1 >> (ns * 8)) & 0xffu));
    }
    __builtin_amdgcn_s_setprio(0);
    VMC4();    // drain kt+1 data+scales; leave kt+2.kw0 in flight
    BARF();
  }

  // epilogue: D mapping row=(lane>>4)*4+r, col=lane&15 per 16x16 block
  float* ob = out + (size_t)(by * BM + wrow * 128) * NDIM + bx * BN + wcol * 64;
#pragma unroll
  for (int ms = 0; ms < 8; ++ms)
#pragma unroll
    for (int ns = 0; ns < 4; ++ns) {
#pragma unroll
      for (int r = 0; r < 4; ++r)
        ob[(size_t)(ms * 16 + g * 4 + r) * NDIM + ns * 16 + l15] = acc[ms][ns][r];
    }
#undef STAGE_HALF
#undef STAGE_SCALES
#undef PLANE
#undef SCB
}

extern "C" void kernel_launch(void* const* d_in, const int* in_sizes, int n_in,
                              void* d_out, int out_size, void* d_ws, size_t ws_size,
                              hipStream_t stream) {
  (void)in_sizes; (void)n_in; (void)out_size; (void)ws_size;
  const int*   a  = (const int*)d_in[0];
  const int*   b  = (const int*)d_in[1];
  const float* sa = (const float*)d_in[2];
  const float* sb = (const float*)d_in[3];
  float* out = (float*)d_out;

  uint8_t* ws = (uint8_t*)d_ws;
  uint32_t* ap = (uint32_t*)ws;                          // 8 MB packed A
  uint32_t* bp = (uint32_t*)(ws + (8u << 20));           // 8 MB packed B
  uint8_t*  satT = ws + (16u << 20);                     // 512 KB scales A (tiled)
  uint8_t*  sbtT = ws + (16u << 20) + (512u << 10);      // 512 KB scales B (tiled)

  repack_bytes<<<2048, 256, 0, stream>>>(a, b, ap, bp);
  repack_scales<<<(MDIM * NKBLK + 255) / 256, 256, 0, stream>>>(sa, sb, satT, sbtT);

  hipFuncSetAttribute((const void*)mxfp4_gemm,
                      hipFuncAttributeMaxDynamicSharedMemorySize, 139264);

  dim3 grid(NDIM / BN, MDIM / BM);   // 16 x 16 = 256 blocks = 1/CU
  mxfp4_gemm<<<grid, 512, 139264, stream>>>((const uint8_t*)ap, (const uint8_t*)bp,
                                            satT, sbtT, out);
}

// Round 8
// 69.341 us; speedup vs baseline: 1.4694x; 1.0287x over previous
//
#include <hip/hip_runtime.h>
#include <hip/hip_bf16.h>
#include <stdint.h>

typedef __attribute__((ext_vector_type(4))) int   i32x4;
typedef __attribute__((ext_vector_type(8))) int   i32x8;
typedef __attribute__((ext_vector_type(4))) float f32x4;
typedef __attribute__((ext_vector_type(2))) unsigned int u32x2;

#define MDIM   4096
#define NDIM   4096
#define KBYTES 2048   // K=4096 fp4 elems -> 2048 packed bytes per row
#define NKBLK  128    // K/32 scale blocks per row

#define BM   256
#define BN   256
#define BKB  128                 // K-bytes per tile (= 256 fp4 elems = 8 scale blocks)
#define KT   (KBYTES / BKB)      // 16 K-tiles

#define BARF()  asm volatile("s_barrier" ::: "memory")
#define LGKM0() asm volatile("s_waitcnt lgkmcnt(0)" ::: "memory")
// Counted drain (T4). Per-tile vmem issue: phase A group = 4 data + 4 scale (8),
// phase B group = 4 data. Tile-end outstanding = [leftover kt+1.kw0 (4)]
// [A grp (8)][B grp (4)] = 16; vmcnt(4) drains all of tile kt+1, leaves
// kt+2.kw0 in flight.
#define VMC4()  asm volatile("s_waitcnt vmcnt(4)" ::: "memory")

// ---------------- repack: int32-per-byte -> packed bytes ----------------
__global__ void repack_bytes(const int* __restrict__ a, const int* __restrict__ b,
                             uint32_t* __restrict__ ap, uint32_t* __restrict__ bp) {
  const size_t n4 = (size_t)MDIM * KBYTES / 4;
  for (size_t i = (size_t)blockIdx.x * blockDim.x + threadIdx.x; i < n4;
       i += (size_t)gridDim.x * blockDim.x) {
    i32x4 va = *(const i32x4*)(a + i * 4);
    ap[i] = (uint32_t)(va.x & 255) | ((uint32_t)(va.y & 255) << 8) |
            ((uint32_t)(va.z & 255) << 16) | ((uint32_t)(va.w & 255) << 24);
    i32x4 vb = *(const i32x4*)(b + i * 4);
    bp[i] = (uint32_t)(vb.x & 255) | ((uint32_t)(vb.y & 255) << 8) |
            ((uint32_t)(vb.z & 255) << 16) | ((uint32_t)(vb.w & 255) << 24);
  }
}

// ---- scales: float -> uint8 E8M0, per-(K-tile, 256-row-block) contiguous 2KB ----
// Layout: [kt(16)][rowblk(16)][kbit(8)][m&15 (16)][ (m>>4)&15 (16) ]  (512 KB).
__global__ void repack_scales(const float* __restrict__ sa, const float* __restrict__ sb,
                              uint8_t* __restrict__ satT, uint8_t* __restrict__ sbtT) {
  int t = blockIdx.x * blockDim.x + threadIdx.x;
  if (t >= MDIM * NKBLK) return;
  int m  = t >> 7;     // row
  int kb = t & 127;    // k-block
  int o  = ((((kb >> 3) * 16 + (m >> 8)) * 8 + (kb & 7)) * 16 + (m & 15)) * 16
           + ((m >> 4) & 15);
  satT[o] = (uint8_t)(int)sa[t];
  sbtT[o] = (uint8_t)(int)sb[t];
}

__device__ __forceinline__ i32x8 frag8(i32x4 v) {
  i32x8 r = {v.x, v.y, v.z, v.w, 0, 0, 0, 0};
  return r;
}

__device__ __forceinline__ int sbyte2(u32x2 p, int i) {
  return (int)((i < 4 ? (p.x >> (i * 8)) : (p.y >> ((i - 4) * 8))) & 0xffu);
}

// ---- MXFP4 GEMM: R7 vmem-clean pipeline, merged compiler-scheduled phases -----
// 2 phases/tile (kw0, kw1); no LGKM0 between ds_reads and MFMAs inside a phase
// (compiler emits fine-grained lgkmcnt -> reads overlap MFMAs, m97 mechanism);
// LGKM0 only immediately before each barrier (race-safety for the plane
// overwrite by next-next-tile staging).
// LDS: data [buf(2)][mat(2)][kw(2)][row(256)][64B] = 128 KB; scales at +128K:
//      [buf(2)][A 2KB | B 2KB] = 8 KB. Total 136 KB.
__global__ __launch_bounds__(512, 2) void mxfp4_gemm(
    const uint8_t* __restrict__ ap, const uint8_t* __restrict__ bp,
    const uint8_t* __restrict__ satT, const uint8_t* __restrict__ sbtT,
    float* __restrict__ out) {
  extern __shared__ uint8_t lds[];

  const int tid  = threadIdx.x;
  const int lane = tid & 63;
  const int w    = tid >> 6;        // wave 0..7
  const int wrow = w >> 2;          // 2 M-waves
  const int wcol = w & 3;           // 4 N-waves
  const int g    = lane >> 4;       // k-group 0..3 (32 fp4 elems each)
  const int l15  = lane & 15;

  const int bx = blockIdx.x;
  const int by = blockIdx.y;

  const uint8_t* aBase = ap + (size_t)(by * BM) * KBYTES;
  const uint8_t* bBase = bp + (size_t)(bx * BN) * KBYTES;

  // read-side swizzle (R5/R7, HW-verified conflict-free): LDS[row][d] holds
  // global slot d ^ ((row>>1)&3); fragment rows have (row>>1)&3 == (l15>>1)&3.
  const int rdslot = (g ^ ((l15 >> 1) & 3)) * 16;
  const int soff4 = (lane >> 2) * KBYTES + (((lane & 3) ^ ((lane >> 3) & 3)) * 16);
  const int arow0 = w * 32;         // each wave stages 32 A-rows + 32 B-rows

#define PLANE(bufi, mat, kwX) (lds + (bufi) * 65536 + (mat) * 32768 + (kwX) * 16384)
#define SCB(bufi)             (lds + 131072 + (bufi) * 4096)

#define STAGE_HALF(bufi, ktX, kwX)                                                        \
  do {                                                                                    \
    const uint8_t* _sa = aBase + (size_t)arow0 * KBYTES + (ktX) * BKB + (kwX) * 64 + soff4; \
    const uint8_t* _sb = bBase + (size_t)arow0 * KBYTES + (ktX) * BKB + (kwX) * 64 + soff4; \
    uint8_t* _da = PLANE(bufi, 0, kwX) + arow0 * 64;                                      \
    uint8_t* _db = PLANE(bufi, 1, kwX) + arow0 * 64;                                      \
    __builtin_amdgcn_global_load_lds((__attribute__((address_space(1))) void*)_sa,        \
        (__attribute__((address_space(3))) void*)_da, 16, 0, 0);                          \
    __builtin_amdgcn_global_load_lds((__attribute__((address_space(1))) void*)(_sa + 16 * KBYTES), \
        (__attribute__((address_space(3))) void*)(_da + 1024), 16, 0, 0);                 \
    __builtin_amdgcn_global_load_lds((__attribute__((address_space(1))) void*)_sb,        \
        (__attribute__((address_space(3))) void*)(_db), 16, 0, 0);                        \
    __builtin_amdgcn_global_load_lds((__attribute__((address_space(1))) void*)(_sb + 16 * KBYTES), \
        (__attribute__((address_space(3))) void*)(_db + 1024), 16, 0, 0);                 \
  } while (0)

// All 8 waves stage the tile's 4 KB of scales redundantly (identical values;
// keeps per-wave vmcnt accounting uniform).
#define STAGE_SCALES(bufi, ktX)                                                           \
  do {                                                                                    \
    const uint8_t* _ssa = satT + ((size_t)(ktX) * 16 + by) * 2048 + lane * 16;            \
    const uint8_t* _ssb = sbtT + ((size_t)(ktX) * 16 + bx) * 2048 + lane * 16;            \
    uint8_t* _dsc = SCB(bufi);                                                            \
    __builtin_amdgcn_global_load_lds((__attribute__((address_space(1))) void*)_ssa,       \
        (__attribute__((address_space(3))) void*)_dsc, 16, 0, 0);                         \
    __builtin_amdgcn_global_load_lds((__attribute__((address_space(1))) void*)(_ssa + 1024), \
        (__attribute__((address_space(3))) void*)(_dsc + 1024), 16, 0, 0);                \
    __builtin_amdgcn_global_load_lds((__attribute__((address_space(1))) void*)_ssb,       \
        (__attribute__((address_space(3))) void*)(_dsc + 2048), 16, 0, 0);                \
    __builtin_amdgcn_global_load_lds((__attribute__((address_space(1))) void*)(_ssb + 1024), \
        (__attribute__((address_space(3))) void*)(_dsc + 3072), 16, 0, 0);                \
  } while (0)

  f32x4 acc[8][4] = {};
  i32x4 a0[4], a1[4], bf[4];

  // ---------------- prologue ----------------
  STAGE_HALF(0, 0, 0);
  STAGE_SCALES(0, 0);            // G1 = 8 ops
  STAGE_HALF(0, 0, 1);           // G2 = 4 ops
  STAGE_HALF(1, 1, 0);           // G3 = 4 ops
  VMC4();                        // drain G1+G2 (tile 0 complete); G3 in flight
  BARF();

  for (int kt = 0; kt < KT; ++kt) {
    const int cur = kt & 1;
    const int nxt = cur ^ 1;
    const uint8_t* A0  = PLANE(cur, 0, 0);
    const uint8_t* B0  = PLANE(cur, 1, 0);
    const uint8_t* A1p = PLANE(cur, 0, 1);
    const uint8_t* B1p = PLANE(cur, 1, 1);
    const int kt1 = (kt + 1) & (KT - 1);   // tail wraps stage junk into dead slots
    const int kt2 = (kt + 2) & (KT - 1);

    // ===== Phase A (kw0): issue {kt+1.kw1 + kt+1 scales}; reads; 32 MFMA ========
    STAGE_HALF(nxt, kt1, 1);
    STAGE_SCALES(nxt, kt1);
    const uint8_t* scb = SCB(cur);
    const u32x2    sAk0 = *(const u32x2*)(scb + (0 + g) * 256 + l15 * 16 + wrow * 8);
    const u32x2    sAk1 = *(const u32x2*)(scb + (4 + g) * 256 + l15 * 16 + wrow * 8);
    const uint32_t sBk0 = *(const uint32_t*)(scb + 2048 + (0 + g) * 256 + l15 * 16 + wcol * 4);
    const uint32_t sBk1 = *(const uint32_t*)(scb + 2048 + (4 + g) * 256 + l15 * 16 + wcol * 4);
#pragma unroll
    for (int ns = 0; ns < 4; ++ns)
      bf[ns] = *(const i32x4*)(B0 + (wcol * 64 + ns * 16 + l15) * 64 + rdslot);
#pragma unroll
    for (int ms = 0; ms < 4; ++ms)
      a0[ms] = *(const i32x4*)(A0 + (wrow * 128 + ms * 16 + l15) * 64 + rdslot);
#pragma unroll
    for (int ms = 0; ms < 4; ++ms)
      a1[ms] = *(const i32x4*)(A0 + (wrow * 128 + (ms + 4) * 16 + l15) * 64 + rdslot);
    // 32 MFMAs; NO explicit lgkm wait -> compiler interleaves reads & MFMAs
#pragma unroll
    for (int ms = 0; ms < 4; ++ms) {
      const int sa = sbyte2(sAk0, ms);
#pragma unroll
      for (int ns = 0; ns < 4; ++ns)
        acc[ms][ns] = __builtin_amdgcn_mfma_scale_f32_16x16x128_f8f6f4(
            frag8(a0[ms]), frag8(bf[ns]), acc[ms][ns], 4, 4,
            0, sa, 0, (int)((sBk0 >> (ns * 8)) & 0xffu));
    }
#pragma unroll
    for (int ms = 0; ms < 4; ++ms) {
      const int sa = sbyte2(sAk0, ms + 4);
#pragma unroll
      for (int ns = 0; ns < 4; ++ns)
        acc[ms + 4][ns] = __builtin_amdgcn_mfma_scale_f32_16x16x128_f8f6f4(
            frag8(a1[ms]), frag8(bf[ns]), acc[ms + 4][ns], 4, 4,
            0, sa, 0, (int)((sBk0 >> (ns * 8)) & 0xffu));
    }
    // drain ALL this wave's LDS reads before the barrier (unconditional), so the
    // phase-B overwrite of the kw0 planes can never race an in-flight read.
    LGKM0();
    BARF();

    // ===== Phase B (kw1): issue {kt+2.kw0}; reads; 32 MFMA; counted drain =======
    STAGE_HALF(cur, kt2, 0);    // overwrites kw0 planes -- safe after barrier
#pragma unroll
    for (int ns = 0; ns < 4; ++ns)
      bf[ns] = *(const i32x4*)(B1p + (wcol * 64 + ns * 16 + l15) * 64 + rdslot);
#pragma unroll
    for (int ms = 0; ms < 4; ++ms)
      a0[ms] = *(const i32x4*)(A1p + (wrow * 128 + ms * 16 + l15) * 64 + rdslot);
#pragma unroll
    for (int ms = 0; ms < 4; ++ms)
      a1[ms] = *(const i32x4*)(A1p + (wrow * 128 + (ms + 4) * 16 + l15) * 64 + rdslot);
#pragma unroll
    for (int ms = 0; ms < 4; ++ms) {
      const int sa = sbyte2(sAk1, ms);
#pragma unroll
      for (int ns = 0; ns < 4; ++ns)
        acc[ms][ns] = __builtin_amdgcn_mfma_scale_f32_16x16x128_f8f6f4(
            frag8(a0[ms]), frag8(bf[ns]), acc[ms][ns], 4, 4,
            0, sa, 0, (int)((sBk1 >> (ns * 8)) & 0xffu));
    }
#pragma unroll
    for (int ms = 0; ms < 4; ++ms) {
      const int sa = sbyte2(sAk1, ms + 4);
#pragma unroll
      for (int ns = 0; ns < 4; ++ns)
        acc[ms + 4][ns] = __builtin_amdgcn_mfma_scale_f32_16x16x128_f8f6f4(
            frag8(a1[ms]), frag8(bf[ns]), acc[ms + 4][ns], 4, 4,
            0, sa, 0, (int)((sBk1 >> (ns * 8)) & 0xffu));
    }
    LGKM0();
    VMC4();    // drain kt+1 data+scales; leave kt+2.kw0 in flight
    BARF();
  }

  // epilogue: D mapping row=(lane>>4)*4+r, col=lane&15 per 16x16 block
  float* ob = out + (size_t)(by * BM + wrow * 128) * NDIM + bx * BN + wcol * 64;
#pragma unroll
  for (int ms = 0; ms < 8; ++ms)
#pragma unroll
    for (int ns = 0; ns < 4; ++ns) {
#pragma unroll
      for (int r = 0; r < 4; ++r)
        ob[(size_t)(ms * 16 + g * 4 + r) * NDIM + ns * 16 + l15] = acc[ms][ns][r];
    }
#undef STAGE_HALF
#undef STAGE_SCALES
#undef PLANE
#undef SCB
}

extern "C" void kernel_launch(void* const* d_in, const int* in_sizes, int n_in,
                              void* d_out, int out_size, void* d_ws, size_t ws_size,
                              hipStream_t stream) {
  (void)in_sizes; (void)n_in; (void)out_size; (void)ws_size;
  const int*   a  = (const int*)d_in[0];
  const int*   b  = (const int*)d_in[1];
  const float* sa = (const float*)d_in[2];
  const float* sb = (const float*)d_in[3];
  float* out = (float*)d_out;

  uint8_t* ws = (uint8_t*)d_ws;
  uint32_t* ap = (uint32_t*)ws;                          // 8 MB packed A
  uint32_t* bp = (uint32_t*)(ws + (8u << 20));           // 8 MB packed B
  uint8_t*  satT = ws + (16u << 20);                     // 512 KB scales A (tiled)
  uint8_t*  sbtT = ws + (16u << 20) + (512u << 10);      // 512 KB scales B (tiled)

  repack_bytes<<<2048, 256, 0, stream>>>(a, b, ap, bp);
  repack_scales<<<(MDIM * NKBLK + 255) / 256, 256, 0, stream>>>(sa, sb, satT, sbtT);

  hipFuncSetAttribute((const void*)mxfp4_gemm,
                      hipFuncAttributeMaxDynamicSharedMemorySize, 139264);

  dim3 grid(NDIM / BN, MDIM / BM);   // 16 x 16 = 256 blocks = 1/CU
  mxfp4_gemm<<<grid, 512, 139264, stream>>>((const uint8_t*)ap, (const uint8_t*)bp,
                                            satT, sbtT, out);
}